// Round 8
// baseline (205.982 us; speedup 1.0000x reference)
//
#include <hip/hip_runtime.h>
#include <math.h>

#define NB 16      // batch
#define NC 3       // obs channels
#define NN 3000    // nodes
#define NT 50      // time
#define NE 96000   // edges
#define NR 3       // relations
#define NS 500     // selected stocks
#define NF 43      // feature dim
#define NFP 44     // padded feature dim
#define NBF (NB*NFP)   // 704 = 11 * 64: transposed row length per node
#define NBKT (NR*NN)   // 9000 buckets keyed (rel, dst)
#define CAP 96     // fixed bucket capacity (mean 10.7; Poisson tail @96 ~ 0)
#define PREF 24    // prefetched indices per bucket (P(cv>24) ~ 1e-5)
#define NHB 8      // batch rows per rgcn pass (half)
#define NHF (NHB*NFP)  // 352 floats per half-row

// ---------------- workspace layout (floats, then ints) ----------------
#define XT_OFF   0
#define H1_OFF   (XT_OFF + NN*NBF)
#define LG_OFF   (H1_OFF + NN*NBF)
#define INT_BASE (LG_OFF + NB*(NS+1))
#define CNT_OFF  0
#define EBUF_OFF (CNT_OFF + NBKT)

// ---------------- fused front: temporal features (A/B split) + bucket fill ----------------
// R7: VGPR DIET (68 -> target <=64; kernel sat one reg past the 64-VGPR
// occupancy cliff, ~2 blocks/CU resident, 4 serial grid rounds):
//  - phase A: wS loaded in two 8-wide halves (j=0..5 then 6..11), 42->24 regs,
//    identical j/FMA order -> bit-identical.
//  - phase B: single-buffer sequential channel loop (was 2-buffer pipeline,
//    56 regs live). Same c order -> bit-identical. Lost intra-wave overlap is
//    repaid by doubled resident waves.
// R1/R2 lesson: k_front is NOT traffic-bound (staging halved FETCH, zero time
// change) - do not re-add LDS staging. No launch-bounds clamp (R5 lesson).
__global__ __launch_bounds__(256, 3) void k_front(
    const float* __restrict__ obs,
    const float* __restrict__ ws1, const float* __restrict__ bs1,
    const float* __restrict__ ws2, const float* __restrict__ bs2,
    const float* __restrict__ wm1, const float* __restrict__ bm1,
    const float* __restrict__ wm2, const float* __restrict__ bm2,
    float* __restrict__ x,
    const int* __restrict__ ei, const int* __restrict__ et,
    int* __restrict__ cnt, int* __restrict__ ebuf)
{
    __shared__ float sp[4][64][23];   // [wave][node][partial]
    int tid = threadIdx.x;

    if (blockIdx.x >= 1500) {
        // ---- bucket fill: 375 blocks x 256 = 96000 exact ----
        int e = (blockIdx.x - 1500) * 256 + tid;
        int bkt = et[e] * NN + ei[NE + e];
        int pos = atomicAdd(&cnt[bkt], 1);
        if (pos < CAP) ebuf[bkt * CAP + pos] = ei[e];  // src
        return;
    }

    int wave = __builtin_amdgcn_readfirstlane(tid >> 6);
    int lane = tid & 63;

    if (blockIdx.x < 750) {
        // ---- phase A: short conv, slice of 12 t's per wave, 2 reg-halves ----
        int idx = blockIdx.x * 64 + lane;
        int b = idx / NN, n = idx - b * NN;
        int base = 12 * wave;
        float acc[20];
        #pragma unroll
        for (int o = 0; o < 20; ++o) acc[o] = 0.f;

        #pragma unroll
        for (int hh = 0; hh < 2; ++hh) {
            int hbase = base + 6 * hh;          // 12w, 12w+6: both even -> float2 ok
            float wS[3][8];
            #pragma unroll
            for (int c = 0; c < 3; ++c) {
                const float2* p2 = (const float2*)(obs + ((size_t)(b * NC + c) * NN + n) * NT + hbase);
                #pragma unroll
                for (int jj = 0; jj < 4; ++jj) {
                    float2 u = p2[jj];
                    wS[c][2 * jj] = u.x; wS[c][2 * jj + 1] = u.y;
                }
            }
            #pragma unroll
            for (int j = 0; j < 6; ++j) {
                float y[3];
                #pragma unroll
                for (int c = 0; c < 3; ++c) {
                    float s = bs1[c];
                    #pragma unroll
                    for (int i = 0; i < 3; ++i)
                        #pragma unroll
                        for (int k = 0; k < 3; ++k)
                            s = fmaf(wS[i][j + k], ws1[(c * 3 + i) * 3 + k], s);
                    y[c] = fmaxf(s, 0.f);
                }
                int gt = hbase + j;   // wave-uniform -> scalar loads of ws2
                #pragma unroll
                for (int o = 0; o < 20; ++o) {
                    float a = acc[o];
                    #pragma unroll
                    for (int c = 0; c < 3; ++c)
                        a = fmaf(y[c], ws2[(o * 3 + c) * 48 + gt], a);
                    acc[o] = a;
                }
            }
        }
        #pragma unroll
        for (int o = 0; o < 20; ++o) sp[wave][lane][o] = acc[o];
        __syncthreads();
        // reduce: 64 nodes x 20 outputs = 1280 = 5*256
        #pragma unroll
        for (int q = 0; q < 5; ++q) {
            int item = q * 256 + tid;
            int node = item / 20, o = item - node * 20;
            int g = blockIdx.x * 64 + node;
            int bb = g / NN, nn = g - bb * NN;
            float s = ((sp[0][node][o] + sp[1][node][o]) +
                       (sp[2][node][o] + sp[3][node][o])) + bs2[o];
            x[(size_t)nn * NBF + bb * NFP + o] = fmaxf(s, 0.f);
        }
        return;
    }

    // ---- phase B: mid conv (single-buffer sequential channels) + long max ----
    {
        int idx = (blockIdx.x - 750) * 64 + lane;
        int b = idx / NN, n = idx - b * NN;
        int mbase = (wave < 3) ? 8 * wave : 24;
        int nld   = (wave < 3) ? 14 : 13;    // float2 count (window 28 / 26)
        const float* orow = obs + ((size_t)b * NC * NN + n) * NT + mbase;

        float s[3][8];
        #pragma unroll
        for (int c = 0; c < 3; ++c)
            #pragma unroll
            for (int t = 0; t < 8; ++t) s[c][t] = bm1[c];
        float cmax[3];
        float wA[28];

        #define LOADW(ch)                                                       \
        {                                                                       \
            const float2* p2 = (const float2*)(orow + (size_t)(ch) * NN * NT);  \
            _Pragma("unroll")                                                   \
            for (int jj = 0; jj < 14; ++jj) {                                   \
                if (jj < nld) {                                                 \
                    float2 u = p2[jj];                                          \
                    wA[2 * jj] = u.x; wA[2 * jj + 1] = u.y;                     \
                } else { wA[2 * jj] = 0.f; wA[2 * jj + 1] = 0.f; }              \
            }                                                                   \
        }
        #define COMPW(ii)                                                       \
        {                                                                       \
            float m = wA[0];                                                    \
            _Pragma("unroll")                                                   \
            for (int t = 1; t < 28; ++t) m = fmaxf(m, wA[t]);                   \
            cmax[ii] = m;                                                       \
            _Pragma("unroll")                                                   \
            for (int c = 0; c < 3; ++c)                                         \
                _Pragma("unroll")                                               \
                for (int t = 0; t < 8; ++t) {                                   \
                    float a = s[c][t];                                          \
                    _Pragma("unroll")                                           \
                    for (int k = 0; k < 21; ++k)                                \
                        a = fmaf(wA[t + k], wm1[(c * 3 + (ii)) * 21 + k], a);   \
                    s[c][t] = a;                                                \
                }                                                               \
        }

        LOADW(0) COMPW(0)
        LOADW(1) COMPW(1)
        LOADW(2) COMPW(2)
        #undef LOADW
        #undef COMPW

        float acc[20];
        #pragma unroll
        for (int o = 0; o < 20; ++o) acc[o] = 0.f;
        int cntM = (wave < 3) ? 8 : 6;
        #pragma unroll
        for (int j = 0; j < 8; ++j) {
            if (j < cntM) {
                float y0 = fmaxf(s[0][j], 0.f);
                float y1 = fmaxf(s[1][j], 0.f);
                float y2 = fmaxf(s[2][j], 0.f);
                int gt = mbase + j;   // wave-uniform -> scalar loads of wm2
                #pragma unroll
                for (int o = 0; o < 20; ++o) {
                    float a = acc[o];
                    a = fmaf(y0, wm2[(o * 3 + 0) * 30 + gt], a);
                    a = fmaf(y1, wm2[(o * 3 + 1) * 30 + gt], a);
                    a = fmaf(y2, wm2[(o * 3 + 2) * 30 + gt], a);
                    acc[o] = a;
                }
            }
        }
        #pragma unroll
        for (int o = 0; o < 20; ++o) sp[wave][lane][o] = acc[o];
        #pragma unroll
        for (int c = 0; c < 3; ++c) sp[wave][lane][20 + c] = cmax[c];
    }
    __syncthreads();
    // reduce mid + long: 64 nodes x 23 = 1472 items
    #pragma unroll
    for (int q = 0; q < 6; ++q) {
        int item = q * 256 + tid;
        if (item < 1472) {
            int node = item / 23, o = item - node * 23;
            int g = (blockIdx.x - 750) * 64 + node;
            int bb = g / NN, nn = g - bb * NN;
            size_t row = (size_t)nn * NBF + bb * NFP;
            if (o < 20) {
                float s = ((sp[0][node][o] + sp[1][node][o]) +
                           (sp[2][node][o] + sp[3][node][o])) + bm2[o];
                x[row + 20 + o] = fmaxf(s, 0.f);
            } else {
                float m = fmaxf(fmaxf(sp[0][node][o], sp[1][node][o]),
                                fmaxf(sp[2][node][o], sp[3][node][o]));
                x[row + 40 + (o - 20)] = fmaxf(m, 0.f);
            }
        }
    }
}

// ---------------- fused RGCN layer: block per (dst, batch-half) ----------------
// R3: batch-halved + XCD-partitioned (FETCH 78->35MB).
// R4: branch-free grouped gather works (VALU 42->55%) but depth-8 -> VGPR 76,
//     occupancy cliff -> net loss.
// R5 LESSON: __launch_bounds__(256,8) forced VGPR=32 and SPILLED (88us).
// R6 (WINNER): plain bounds + depth-4 groups + wsl loaded after gather.
//     DO NOT TOUCH.
template<bool LEAKY, bool SEL>
__global__ __launch_bounds__(256) void k_rgcn(
    const float* __restrict__ in, const float* __restrict__ xsrc,
    const int* __restrict__ cnt, const int* __restrict__ ebuf,
    const int* __restrict__ sel,
    const float* __restrict__ root, const float* __restrict__ rel,
    const float* __restrict__ bias,
    const float* __restrict__ la, const float* __restrict__ wf,
    const float* __restrict__ bf,
    float* __restrict__ out)
{
    __shared__ __align__(16) float lrow[4][NHF];  // self | z0 | z1 | z2 (5632 B)
    __shared__ float sP[NHB][4][NFP];             // partials (5632 B)

    int tid = threadIdx.x;
    int wave = __builtin_amdgcn_readfirstlane(tid >> 6);
    int lane = tid & 63;

    // decode (idx, half): bids 0-3 -> half 0 (XCDs 0-3), 4-7 -> half 1
    int bid = blockIdx.x;
    int g = bid >> 3, r = bid & 7;
    int half = (r >> 2) & 1;
    int idx = g * 4 + (r & 3);              // 0..NN-1 (L1) or 0..NS-1 (L2)
    int node = __builtin_amdgcn_readfirstlane(SEL ? sel[idx] : idx);
    const float* inh = in + (size_t)node * NBF + half * NHF;

    #define LK4(t)                                              \
        if (LEAKY) {                                            \
            t.x = t.x >= 0.f ? t.x : 0.01f * t.x;               \
            t.y = t.y >= 0.f ? t.y : 0.01f * t.y;               \
            t.z = t.z >= 0.f ? t.z : 0.01f * t.z;               \
            t.w = t.w >= 0.f ? t.w : 0.01f * t.w;               \
        }

    // ---- phase 1 (wsl intentionally NOT yet loaded: gather needs the regs) ----
    if (wave == 3) {
        // self half-row: 88 float4
        const float4* p4 = (const float4*)inh;
        float4 v0 = p4[lane];
        LK4(v0)
        *(float4*)&lrow[0][4 * lane] = v0;
        if (lane < 24) {
            float4 v1 = p4[64 + lane];
            LK4(v1)
            *(float4*)&lrow[0][4 * (64 + lane)] = v1;
        }
    } else {
        int bkt = wave * NN + node;
        int cvr = __builtin_amdgcn_readfirstlane(cnt[bkt]);
        float ic = 1.0f / fmaxf((float)cvr, 1.0f);
        int cv = cvr > CAP ? CAP : cvr;
        const int* eb = ebuf + (size_t)bkt * CAP;

        // prefetch all (typical) indices: wave-uniform address -> scalar
        // loads; garbage beyond cv is never used as an address (safe select).
        int id[PREF];
        #pragma unroll
        for (int k = 0; k < PREF / 4; ++k) {
            int4 q = *(const int4*)(eb + 4 * k);
            id[4 * k + 0] = __builtin_amdgcn_readfirstlane(q.x);
            id[4 * k + 1] = __builtin_amdgcn_readfirstlane(q.y);
            id[4 * k + 2] = __builtin_amdgcn_readfirstlane(q.z);
            id[4 * k + 3] = __builtin_amdgcn_readfirstlane(q.w);
        }

        float4 a0 = {0.f, 0.f, 0.f, 0.f};
        float4 a1 = {0.f, 0.f, 0.f, 0.f};
        int ng = (cv + 3) & ~3;   // groups of 4

        // branch-free predicated groups of 4 edges (8 float4 in flight)
        #pragma unroll
        for (int grp = 0; grp < PREF; grp += 4) {
            if (grp < ng) {   // wave-uniform; at most 6 branches
                float4 v0[4], v1[4];
                float w[4];
                #pragma unroll
                for (int u = 0; u < 4; ++u) {
                    int e = grp + u;
                    int ie = id[e < cv ? e : 0];      // cv>=1 when ng>0
                    w[u] = (e < cv) ? 1.f : 0.f;
                    const float4* p = (const float4*)(in + (size_t)ie * NBF + half * NHF);
                    v0[u] = p[lane];
                    if (lane < 24) v1[u] = p[64 + lane];
                }
                #pragma unroll
                for (int u = 0; u < 4; ++u) {
                    float4 t0 = v0[u];
                    LK4(t0)
                    a0.x = fmaf(w[u], t0.x, a0.x);
                    a0.y = fmaf(w[u], t0.y, a0.y);
                    a0.z = fmaf(w[u], t0.z, a0.z);
                    a0.w = fmaf(w[u], t0.w, a0.w);
                    if (lane < 24) {
                        float4 t1 = v1[u];
                        LK4(t1)
                        a1.x = fmaf(w[u], t1.x, a1.x);
                        a1.y = fmaf(w[u], t1.y, a1.y);
                        a1.z = fmaf(w[u], t1.z, a1.z);
                        a1.w = fmaf(w[u], t1.w, a1.w);
                    }
                }
            }
        }
        // rare overflow tail (P ~ 1e-5), serial
        for (int e = PREF; e < cv; ++e) {
            int i0 = __builtin_amdgcn_readfirstlane(eb[e]);
            const float4* p = (const float4*)(in + (size_t)i0 * NBF + half * NHF);
            float4 t0 = p[lane];
            LK4(t0)
            a0.x += t0.x; a0.y += t0.y; a0.z += t0.z; a0.w += t0.w;
            if (lane < 24) {
                float4 t1 = p[64 + lane];
                LK4(t1)
                a1.x += t1.x; a1.y += t1.y; a1.z += t1.z; a1.w += t1.w;
            }
        }

        float* dst = &lrow[wave + 1][0];
        a0.x *= ic; a0.y *= ic; a0.z *= ic; a0.w *= ic;
        *(float4*)&dst[4 * lane] = a0;
        if (lane < 24) {
            a1.x *= ic; a1.y *= ic; a1.z *= ic; a1.w *= ic;
            *(float4*)&dst[4 * (64 + lane)] = a1;
        }
    }
    #undef LK4

    // weight column loaded AFTER the gather (frees 43 VGPRs during it).
    // sched_barrier(0) stops the compiler hoisting these loads back up.
    __builtin_amdgcn_sched_barrier(0);
    const float* wbase = (wave == 0) ? root : (rel + (size_t)(wave - 1) * NF * NF);
    float wsl[43];
    #pragma unroll
    for (int j = 0; j < 43; ++j)
        wsl[j] = (lane < NF) ? wbase[j * NF + lane] : 0.f;
    __syncthreads();

    // ---- phase 2: 8 batch-rows, single pass ----
    #pragma unroll
    for (int rr = 0; rr < NHB; ++rr) {
        const float4* a4 = (const float4*)&lrow[wave][rr * NFP];  // LDS broadcast
        float a0 = 0.f, a1 = 0.f, a2 = 0.f, a3 = 0.f;
        #pragma unroll
        for (int c = 0; c < 10; ++c) {
            float4 v = a4[c];
            a0 = fmaf(v.x, wsl[4 * c], a0);
            a1 = fmaf(v.y, wsl[4 * c + 1], a1);
            a2 = fmaf(v.z, wsl[4 * c + 2], a2);
            a3 = fmaf(v.w, wsl[4 * c + 3], a3);
        }
        {
            float4 v = a4[10];   // j = 40..43 (43 is pad, skipped)
            a0 = fmaf(v.x, wsl[40], a0);
            a1 = fmaf(v.y, wsl[41], a1);
            a2 = fmaf(v.z, wsl[42], a2);
        }
        if (lane < NF) sP[rr][wave][lane] = (a0 + a1) + (a2 + a3);
    }
    __syncthreads();

    // each wave reduces 2 rows
    int r0 = 2 * wave, r1 = 2 * wave + 1;
    int b0 = half * NHB + r0, b1 = half * NHB + r1;
    if (!SEL) {
        if (lane < NF) {
            float bi_ = bias[lane];
            float s0 = ((sP[r0][0][lane] + sP[r0][1][lane]) +
                        (sP[r0][2][lane] + sP[r0][3][lane])) + bi_;
            float s1 = ((sP[r1][0][lane] + sP[r1][1][lane]) +
                        (sP[r1][2][lane] + sP[r1][3][lane])) + bi_;
            out[(size_t)idx * NBF + b0 * NFP + lane] = s0;
            out[(size_t)idx * NBF + b1 * NFP + lane] = s1;
        }
    } else {
        // logits: lg[b] = bf + wf0*la + sum_f wf1[f]*x[f] + wf2[f]*leaky(h2[f])
        float p0 = 0.f, p1 = 0.f;
        if (lane < NF) {
            float bi_ = bias[lane];
            float s0 = ((sP[r0][0][lane] + sP[r0][1][lane]) +
                        (sP[r0][2][lane] + sP[r0][3][lane])) + bi_;
            float s1 = ((sP[r1][0][lane] + sP[r1][1][lane]) +
                        (sP[r1][2][lane] + sP[r1][3][lane])) + bi_;
            s0 = s0 >= 0.f ? s0 : 0.01f * s0;
            s1 = s1 >= 0.f ? s1 : 0.01f * s1;
            float x0 = xsrc[(size_t)node * NBF + b0 * NFP + lane];
            float x1 = xsrc[(size_t)node * NBF + b1 * NFP + lane];
            p0 = fmaf(wf[44 + lane], s0, wf[1 + lane] * x0);
            p1 = fmaf(wf[44 + lane], s1, wf[1 + lane] * x1);
        }
        #pragma unroll
        for (int o = 32; o > 0; o >>= 1) {
            p0 += __shfl_down(p0, o);
            p1 += __shfl_down(p1, o);
        }
        if (lane == 0) {
            out[(size_t)b0 * (NS + 1) + 1 + idx] =
                p0 + bf[0] + wf[0] * la[b0 * (NS + 1) + 1 + idx];
            out[(size_t)b1 * (NS + 1) + 1 + idx] =
                p1 + bf[0] + wf[0] * la[b1 * (NS + 1) + 1 + idx];
        }
    }
}

// ---------------- softmax over 501 logits per batch ----------------
__device__ inline float wred_max(float v) {
    #pragma unroll
    for (int o = 32; o > 0; o >>= 1) v = fmaxf(v, __shfl_down(v, o));
    return v;
}
__device__ inline float wred_sum(float v) {
    #pragma unroll
    for (int o = 32; o > 0; o >>= 1) v += __shfl_down(v, o);
    return v;
}

__global__ __launch_bounds__(512) void k_softmax(
    const float* __restrict__ lg, float* __restrict__ out)
{
    __shared__ float sred[8];
    __shared__ float sbc[2];
    int b = blockIdx.x, tid = threadIdx.x;

    float val = -3.0e38f;
    if (tid <= NS) val = (tid == 0) ? 0.f : lg[(size_t)b * (NS + 1) + tid];

    float m = wred_max(val);
    if ((tid & 63) == 0) sred[tid >> 6] = m;
    __syncthreads();
    if (tid == 0) {
        float mm = sred[0];
        #pragma unroll
        for (int i = 1; i < 8; ++i) mm = fmaxf(mm, sred[i]);
        sbc[0] = mm;
    }
    __syncthreads();
    float mx = sbc[0];
    float e = (tid <= NS) ? expf(val - mx) : 0.f;
    float s = wred_sum(e);
    if ((tid & 63) == 0) sred[tid >> 6] = s;
    __syncthreads();
    if (tid == 0) {
        float t = 0.f;
        #pragma unroll
        for (int i = 0; i < 8; ++i) t += sred[i];
        sbc[1] = t;
    }
    __syncthreads();
    if (tid <= NS) out[(size_t)b * (NS + 1) + tid] = e / sbc[1];
}

extern "C" void kernel_launch(void* const* d_in, const int* in_sizes, int n_in,
                              void* d_out, int out_size, void* d_ws, size_t ws_size,
                              hipStream_t stream)
{
    const float* obs   = (const float*)d_in[0];
    const float* la    = (const float*)d_in[1];
    const int*   ei    = (const int*)d_in[2];
    const int*   et    = (const int*)d_in[3];
    const int*   nodes = (const int*)d_in[4];
    const float* ws1 = (const float*)d_in[5],  *bs1 = (const float*)d_in[6];
    const float* ws2 = (const float*)d_in[7],  *bs2 = (const float*)d_in[8];
    const float* wm1 = (const float*)d_in[9],  *bm1 = (const float*)d_in[10];
    const float* wm2 = (const float*)d_in[11], *bm2 = (const float*)d_in[12];
    const float* root1 = (const float*)d_in[13], *rel1 = (const float*)d_in[14], *bias1 = (const float*)d_in[15];
    const float* root2 = (const float*)d_in[16], *rel2 = (const float*)d_in[17], *bias2 = (const float*)d_in[18];
    const float* wf = (const float*)d_in[19], *bf = (const float*)d_in[20];

    float* wsp = (float*)d_ws;
    float* x   = wsp + XT_OFF;
    float* h1  = wsp + H1_OFF;
    float* lg  = wsp + LG_OFF;
    int*   ibase = (int*)(wsp + INT_BASE);
    int*   cnt   = ibase + CNT_OFF;
    int*   ebuf  = ibase + EBUF_OFF;

    hipMemsetAsync(cnt, 0, NBKT * sizeof(int), stream);

    // fused: phase A (0..749) + phase B (750..1499) + bucket fill (1500..1874)
    k_front<<<1875, 256, 0, stream>>>(
        obs, ws1, bs1, ws2, bs2, wm1, bm1, wm2, bm2, x, ei, et, cnt, ebuf);

    // RGCN layer 1: block per (node, batch-half), XCD-partitioned halves
    k_rgcn<false, false><<<NN * 2, 256, 0, stream>>>(
        x, nullptr, cnt, ebuf, nullptr, root1, rel1, bias1,
        nullptr, nullptr, nullptr, h1);

    // RGCN layer 2 (+ logits): block per (selected stock, batch-half)
    k_rgcn<true, true><<<NS * 2, 256, 0, stream>>>(
        h1, x, cnt, ebuf, nodes, root2, rel2, bias2,
        la, wf, bf, lg);

    k_softmax<<<NB, 512, 0, stream>>>(lg, (float*)d_out);
}

// Round 9
// 200.669 us; speedup vs baseline: 1.0265x; 1.0265x over previous
//
#include <hip/hip_runtime.h>
#include <math.h>

#define NB 16      // batch
#define NC 3       // obs channels
#define NN 3000    // nodes
#define NT 50      // time
#define NE 96000   // edges
#define NR 3       // relations
#define NS 500     // selected stocks
#define NF 43      // feature dim
#define NFP 44     // padded feature dim
#define NBF (NB*NFP)   // 704 = 11 * 64: transposed row length per node
#define NBKT (NR*NN)   // 9000 buckets keyed (rel, dst)
#define CAP 96     // fixed bucket capacity (mean 10.7; Poisson tail @96 ~ 0)
#define PREF 24    // prefetched indices per bucket (P(cv>24) ~ 1e-5)
#define NHB 8      // batch rows per rgcn pass (half)
#define NHF (NHB*NFP)  // 352 floats per half-row

// ---------------- workspace layout (floats, then ints) ----------------
#define XT_OFF   0
#define H1_OFF   (XT_OFF + NN*NBF)
#define LG_OFF   (H1_OFF + NN*NBF)
#define INT_BASE (LG_OFF + NB*(NS+1))
#define CNT_OFF  0
#define EBUF_OFF (CNT_OFF + NBKT)

// ---------------- fused front: temporal features (A/B split) + bucket fill ----------------
// R8: EXACT session-start baseline form (proven 45.9us). Ledger of failed
// alternatives — do not revisit:
//   R1/R2 LDS staging (split 49.2 / merged 48.0): FETCH halved, time flat ->
//     not traffic-bound.
//   R7 VGPR diet + single-buffer phase B (77-85us): VGPR stayed 68 (allocator
//     uses its (256,3) budget regardless of live-range shrink); removing the
//     two-buffer pipeline serialized loads (VALUBusy 43->25%).
// NOTE: __launch_bounds__(256,3) — (256,4) forces lower VGPR and SPILLS. Keep 3.
__global__ __launch_bounds__(256, 3) void k_front(
    const float* __restrict__ obs,
    const float* __restrict__ ws1, const float* __restrict__ bs1,
    const float* __restrict__ ws2, const float* __restrict__ bs2,
    const float* __restrict__ wm1, const float* __restrict__ bm1,
    const float* __restrict__ wm2, const float* __restrict__ bm2,
    float* __restrict__ x,
    const int* __restrict__ ei, const int* __restrict__ et,
    int* __restrict__ cnt, int* __restrict__ ebuf)
{
    __shared__ float sp[4][64][23];   // [wave][node][partial]
    int tid = threadIdx.x;

    if (blockIdx.x >= 1500) {
        // ---- bucket fill: 375 blocks x 256 = 96000 exact ----
        int e = (blockIdx.x - 1500) * 256 + tid;
        int bkt = et[e] * NN + ei[NE + e];
        int pos = atomicAdd(&cnt[bkt], 1);
        if (pos < CAP) ebuf[bkt * CAP + pos] = ei[e];  // src
        return;
    }

    int wave = __builtin_amdgcn_readfirstlane(tid >> 6);
    int lane = tid & 63;

    if (blockIdx.x < 750) {
        // ---- phase A: short conv, slice of 12 t's per wave ----
        int idx = blockIdx.x * 64 + lane;
        int b = idx / NN, n = idx - b * NN;
        float wS[3][14];
        int base = 12 * wave;
        #pragma unroll
        for (int c = 0; c < 3; ++c) {
            const float2* p2 = (const float2*)(obs + ((size_t)(b * NC + c) * NN + n) * NT + base);
            #pragma unroll
            for (int jj = 0; jj < 7; ++jj) {
                float2 u = p2[jj];
                wS[c][2 * jj] = u.x; wS[c][2 * jj + 1] = u.y;
            }
        }
        float acc[20];
        #pragma unroll
        for (int o = 0; o < 20; ++o) acc[o] = 0.f;
        #pragma unroll
        for (int j = 0; j < 12; ++j) {
            float y[3];
            #pragma unroll
            for (int c = 0; c < 3; ++c) {
                float s = bs1[c];
                #pragma unroll
                for (int i = 0; i < 3; ++i)
                    #pragma unroll
                    for (int k = 0; k < 3; ++k)
                        s = fmaf(wS[i][j + k], ws1[(c * 3 + i) * 3 + k], s);
                y[c] = fmaxf(s, 0.f);
            }
            int gt = base + j;   // wave-uniform -> scalar loads of ws2
            #pragma unroll
            for (int o = 0; o < 20; ++o) {
                float a = acc[o];
                #pragma unroll
                for (int c = 0; c < 3; ++c)
                    a = fmaf(y[c], ws2[(o * 3 + c) * 48 + gt], a);
                acc[o] = a;
            }
        }
        #pragma unroll
        for (int o = 0; o < 20; ++o) sp[wave][lane][o] = acc[o];
        __syncthreads();
        // reduce: 64 nodes x 20 outputs = 1280 = 5*256
        #pragma unroll
        for (int q = 0; q < 5; ++q) {
            int item = q * 256 + tid;
            int node = item / 20, o = item - node * 20;
            int g = blockIdx.x * 64 + node;
            int bb = g / NN, nn = g - bb * NN;
            float s = ((sp[0][node][o] + sp[1][node][o]) +
                       (sp[2][node][o] + sp[3][node][o])) + bs2[o];
            x[(size_t)nn * NBF + bb * NFP + o] = fmaxf(s, 0.f);
        }
        return;
    }

    // ---- phase B: mid conv (channel pipelined) + long max ----
    {
        int idx = (blockIdx.x - 750) * 64 + lane;
        int b = idx / NN, n = idx - b * NN;
        int mbase = (wave < 3) ? 8 * wave : 24;
        int nld   = (wave < 3) ? 14 : 13;    // float2 count (window 28 / 26)
        const float* orow = obs + ((size_t)b * NC * NN + n) * NT + mbase;

        float s[3][8];
        #pragma unroll
        for (int c = 0; c < 3; ++c)
            #pragma unroll
            for (int t = 0; t < 8; ++t) s[c][t] = bm1[c];
        float cmax[3];
        float wA[28], wB[28];

        // static double-buffered channel pipeline: load(i+1) overlaps compute(i)
        #define LOADW(buf, ch)                                                  \
        {                                                                       \
            const float2* p2 = (const float2*)(orow + (size_t)(ch) * NN * NT);  \
            _Pragma("unroll")                                                   \
            for (int jj = 0; jj < 14; ++jj) {                                   \
                if (jj < nld) {                                                 \
                    float2 u = p2[jj];                                          \
                    buf[2 * jj] = u.x; buf[2 * jj + 1] = u.y;                   \
                } else { buf[2 * jj] = 0.f; buf[2 * jj + 1] = 0.f; }            \
            }                                                                   \
        }
        #define COMPW(buf, ii)                                                  \
        {                                                                       \
            float m = buf[0];                                                   \
            _Pragma("unroll")                                                   \
            for (int t = 1; t < 28; ++t) m = fmaxf(m, buf[t]);                  \
            cmax[ii] = m;                                                       \
            _Pragma("unroll")                                                   \
            for (int c = 0; c < 3; ++c)                                         \
                _Pragma("unroll")                                               \
                for (int t = 0; t < 8; ++t) {                                   \
                    float a = s[c][t];                                          \
                    _Pragma("unroll")                                           \
                    for (int k = 0; k < 21; ++k)                                \
                        a = fmaf(buf[t + k], wm1[(c * 3 + (ii)) * 21 + k], a);  \
                    s[c][t] = a;                                                \
                }                                                               \
        }

        LOADW(wA, 0)
        LOADW(wB, 1)
        COMPW(wA, 0)
        LOADW(wA, 2)
        COMPW(wB, 1)
        COMPW(wA, 2)
        #undef LOADW
        #undef COMPW

        float acc[20];
        #pragma unroll
        for (int o = 0; o < 20; ++o) acc[o] = 0.f;
        int cntM = (wave < 3) ? 8 : 6;
        #pragma unroll
        for (int j = 0; j < 8; ++j) {
            if (j < cntM) {
                float y0 = fmaxf(s[0][j], 0.f);
                float y1 = fmaxf(s[1][j], 0.f);
                float y2 = fmaxf(s[2][j], 0.f);
                int gt = mbase + j;   // wave-uniform -> scalar loads of wm2
                #pragma unroll
                for (int o = 0; o < 20; ++o) {
                    float a = acc[o];
                    a = fmaf(y0, wm2[(o * 3 + 0) * 30 + gt], a);
                    a = fmaf(y1, wm2[(o * 3 + 1) * 30 + gt], a);
                    a = fmaf(y2, wm2[(o * 3 + 2) * 30 + gt], a);
                    acc[o] = a;
                }
            }
        }
        #pragma unroll
        for (int o = 0; o < 20; ++o) sp[wave][lane][o] = acc[o];
        #pragma unroll
        for (int c = 0; c < 3; ++c) sp[wave][lane][20 + c] = cmax[c];
    }
    __syncthreads();
    // reduce mid + long: 64 nodes x 23 = 1472 items
    #pragma unroll
    for (int q = 0; q < 6; ++q) {
        int item = q * 256 + tid;
        if (item < 1472) {
            int node = item / 23, o = item - node * 23;
            int g = (blockIdx.x - 750) * 64 + node;
            int bb = g / NN, nn = g - bb * NN;
            size_t row = (size_t)nn * NBF + bb * NFP;
            if (o < 20) {
                float s = ((sp[0][node][o] + sp[1][node][o]) +
                           (sp[2][node][o] + sp[3][node][o])) + bm2[o];
                x[row + 20 + o] = fmaxf(s, 0.f);
            } else {
                float m = fmaxf(fmaxf(sp[0][node][o], sp[1][node][o]),
                                fmaxf(sp[2][node][o], sp[3][node][o]));
                x[row + 40 + (o - 20)] = fmaxf(m, 0.f);
            }
        }
    }
}

// ---------------- fused RGCN layer: block per (dst, batch-half) ----------------
// R3: batch-halved + XCD-partitioned (FETCH 78->35MB).
// R4: branch-free grouped gather works (VALU 42->55%) but depth-8 -> VGPR 76,
//     occupancy cliff -> net loss.
// R5 LESSON: __launch_bounds__(256,8) forced VGPR=32 and SPILLED (88us).
// R6 (WINNER, total 200.8us): plain bounds + depth-4 groups + wsl loaded
//     after gather. DO NOT TOUCH.
template<bool LEAKY, bool SEL>
__global__ __launch_bounds__(256) void k_rgcn(
    const float* __restrict__ in, const float* __restrict__ xsrc,
    const int* __restrict__ cnt, const int* __restrict__ ebuf,
    const int* __restrict__ sel,
    const float* __restrict__ root, const float* __restrict__ rel,
    const float* __restrict__ bias,
    const float* __restrict__ la, const float* __restrict__ wf,
    const float* __restrict__ bf,
    float* __restrict__ out)
{
    __shared__ __align__(16) float lrow[4][NHF];  // self | z0 | z1 | z2 (5632 B)
    __shared__ float sP[NHB][4][NFP];             // partials (5632 B)

    int tid = threadIdx.x;
    int wave = __builtin_amdgcn_readfirstlane(tid >> 6);
    int lane = tid & 63;

    // decode (idx, half): bids 0-3 -> half 0 (XCDs 0-3), 4-7 -> half 1
    int bid = blockIdx.x;
    int g = bid >> 3, r = bid & 7;
    int half = (r >> 2) & 1;
    int idx = g * 4 + (r & 3);              // 0..NN-1 (L1) or 0..NS-1 (L2)
    int node = __builtin_amdgcn_readfirstlane(SEL ? sel[idx] : idx);
    const float* inh = in + (size_t)node * NBF + half * NHF;

    #define LK4(t)                                              \
        if (LEAKY) {                                            \
            t.x = t.x >= 0.f ? t.x : 0.01f * t.x;               \
            t.y = t.y >= 0.f ? t.y : 0.01f * t.y;               \
            t.z = t.z >= 0.f ? t.z : 0.01f * t.z;               \
            t.w = t.w >= 0.f ? t.w : 0.01f * t.w;               \
        }

    // ---- phase 1 (wsl intentionally NOT yet loaded: gather needs the regs) ----
    if (wave == 3) {
        // self half-row: 88 float4
        const float4* p4 = (const float4*)inh;
        float4 v0 = p4[lane];
        LK4(v0)
        *(float4*)&lrow[0][4 * lane] = v0;
        if (lane < 24) {
            float4 v1 = p4[64 + lane];
            LK4(v1)
            *(float4*)&lrow[0][4 * (64 + lane)] = v1;
        }
    } else {
        int bkt = wave * NN + node;
        int cvr = __builtin_amdgcn_readfirstlane(cnt[bkt]);
        float ic = 1.0f / fmaxf((float)cvr, 1.0f);
        int cv = cvr > CAP ? CAP : cvr;
        const int* eb = ebuf + (size_t)bkt * CAP;

        // prefetch all (typical) indices: wave-uniform address -> scalar
        // loads; garbage beyond cv is never used as an address (safe select).
        int id[PREF];
        #pragma unroll
        for (int k = 0; k < PREF / 4; ++k) {
            int4 q = *(const int4*)(eb + 4 * k);
            id[4 * k + 0] = __builtin_amdgcn_readfirstlane(q.x);
            id[4 * k + 1] = __builtin_amdgcn_readfirstlane(q.y);
            id[4 * k + 2] = __builtin_amdgcn_readfirstlane(q.z);
            id[4 * k + 3] = __builtin_amdgcn_readfirstlane(q.w);
        }

        float4 a0 = {0.f, 0.f, 0.f, 0.f};
        float4 a1 = {0.f, 0.f, 0.f, 0.f};
        int ng = (cv + 3) & ~3;   // groups of 4

        // branch-free predicated groups of 4 edges (8 float4 in flight)
        #pragma unroll
        for (int grp = 0; grp < PREF; grp += 4) {
            if (grp < ng) {   // wave-uniform; at most 6 branches
                float4 v0[4], v1[4];
                float w[4];
                #pragma unroll
                for (int u = 0; u < 4; ++u) {
                    int e = grp + u;
                    int ie = id[e < cv ? e : 0];      // cv>=1 when ng>0
                    w[u] = (e < cv) ? 1.f : 0.f;
                    const float4* p = (const float4*)(in + (size_t)ie * NBF + half * NHF);
                    v0[u] = p[lane];
                    if (lane < 24) v1[u] = p[64 + lane];
                }
                #pragma unroll
                for (int u = 0; u < 4; ++u) {
                    float4 t0 = v0[u];
                    LK4(t0)
                    a0.x = fmaf(w[u], t0.x, a0.x);
                    a0.y = fmaf(w[u], t0.y, a0.y);
                    a0.z = fmaf(w[u], t0.z, a0.z);
                    a0.w = fmaf(w[u], t0.w, a0.w);
                    if (lane < 24) {
                        float4 t1 = v1[u];
                        LK4(t1)
                        a1.x = fmaf(w[u], t1.x, a1.x);
                        a1.y = fmaf(w[u], t1.y, a1.y);
                        a1.z = fmaf(w[u], t1.z, a1.z);
                        a1.w = fmaf(w[u], t1.w, a1.w);
                    }
                }
            }
        }
        // rare overflow tail (P ~ 1e-5), serial
        for (int e = PREF; e < cv; ++e) {
            int i0 = __builtin_amdgcn_readfirstlane(eb[e]);
            const float4* p = (const float4*)(in + (size_t)i0 * NBF + half * NHF);
            float4 t0 = p[lane];
            LK4(t0)
            a0.x += t0.x; a0.y += t0.y; a0.z += t0.z; a0.w += t0.w;
            if (lane < 24) {
                float4 t1 = p[64 + lane];
                LK4(t1)
                a1.x += t1.x; a1.y += t1.y; a1.z += t1.z; a1.w += t1.w;
            }
        }

        float* dst = &lrow[wave + 1][0];
        a0.x *= ic; a0.y *= ic; a0.z *= ic; a0.w *= ic;
        *(float4*)&dst[4 * lane] = a0;
        if (lane < 24) {
            a1.x *= ic; a1.y *= ic; a1.z *= ic; a1.w *= ic;
            *(float4*)&dst[4 * (64 + lane)] = a1;
        }
    }
    #undef LK4

    // weight column loaded AFTER the gather (frees 43 VGPRs during it).
    // sched_barrier(0) stops the compiler hoisting these loads back up.
    __builtin_amdgcn_sched_barrier(0);
    const float* wbase = (wave == 0) ? root : (rel + (size_t)(wave - 1) * NF * NF);
    float wsl[43];
    #pragma unroll
    for (int j = 0; j < 43; ++j)
        wsl[j] = (lane < NF) ? wbase[j * NF + lane] : 0.f;
    __syncthreads();

    // ---- phase 2: 8 batch-rows, single pass ----
    #pragma unroll
    for (int rr = 0; rr < NHB; ++rr) {
        const float4* a4 = (const float4*)&lrow[wave][rr * NFP];  // LDS broadcast
        float a0 = 0.f, a1 = 0.f, a2 = 0.f, a3 = 0.f;
        #pragma unroll
        for (int c = 0; c < 10; ++c) {
            float4 v = a4[c];
            a0 = fmaf(v.x, wsl[4 * c], a0);
            a1 = fmaf(v.y, wsl[4 * c + 1], a1);
            a2 = fmaf(v.z, wsl[4 * c + 2], a2);
            a3 = fmaf(v.w, wsl[4 * c + 3], a3);
        }
        {
            float4 v = a4[10];   // j = 40..43 (43 is pad, skipped)
            a0 = fmaf(v.x, wsl[40], a0);
            a1 = fmaf(v.y, wsl[41], a1);
            a2 = fmaf(v.z, wsl[42], a2);
        }
        if (lane < NF) sP[rr][wave][lane] = (a0 + a1) + (a2 + a3);
    }
    __syncthreads();

    // each wave reduces 2 rows
    int r0 = 2 * wave, r1 = 2 * wave + 1;
    int b0 = half * NHB + r0, b1 = half * NHB + r1;
    if (!SEL) {
        if (lane < NF) {
            float bi_ = bias[lane];
            float s0 = ((sP[r0][0][lane] + sP[r0][1][lane]) +
                        (sP[r0][2][lane] + sP[r0][3][lane])) + bi_;
            float s1 = ((sP[r1][0][lane] + sP[r1][1][lane]) +
                        (sP[r1][2][lane] + sP[r1][3][lane])) + bi_;
            out[(size_t)idx * NBF + b0 * NFP + lane] = s0;
            out[(size_t)idx * NBF + b1 * NFP + lane] = s1;
        }
    } else {
        // logits: lg[b] = bf + wf0*la + sum_f wf1[f]*x[f] + wf2[f]*leaky(h2[f])
        float p0 = 0.f, p1 = 0.f;
        if (lane < NF) {
            float bi_ = bias[lane];
            float s0 = ((sP[r0][0][lane] + sP[r0][1][lane]) +
                        (sP[r0][2][lane] + sP[r0][3][lane])) + bi_;
            float s1 = ((sP[r1][0][lane] + sP[r1][1][lane]) +
                        (sP[r1][2][lane] + sP[r1][3][lane])) + bi_;
            s0 = s0 >= 0.f ? s0 : 0.01f * s0;
            s1 = s1 >= 0.f ? s1 : 0.01f * s1;
            float x0 = xsrc[(size_t)node * NBF + b0 * NFP + lane];
            float x1 = xsrc[(size_t)node * NBF + b1 * NFP + lane];
            p0 = fmaf(wf[44 + lane], s0, wf[1 + lane] * x0);
            p1 = fmaf(wf[44 + lane], s1, wf[1 + lane] * x1);
        }
        #pragma unroll
        for (int o = 32; o > 0; o >>= 1) {
            p0 += __shfl_down(p0, o);
            p1 += __shfl_down(p1, o);
        }
        if (lane == 0) {
            out[(size_t)b0 * (NS + 1) + 1 + idx] =
                p0 + bf[0] + wf[0] * la[b0 * (NS + 1) + 1 + idx];
            out[(size_t)b1 * (NS + 1) + 1 + idx] =
                p1 + bf[0] + wf[0] * la[b1 * (NS + 1) + 1 + idx];
        }
    }
}

// ---------------- softmax over 501 logits per batch ----------------
__device__ inline float wred_max(float v) {
    #pragma unroll
    for (int o = 32; o > 0; o >>= 1) v = fmaxf(v, __shfl_down(v, o));
    return v;
}
__device__ inline float wred_sum(float v) {
    #pragma unroll
    for (int o = 32; o > 0; o >>= 1) v += __shfl_down(v, o);
    return v;
}

__global__ __launch_bounds__(512) void k_softmax(
    const float* __restrict__ lg, float* __restrict__ out)
{
    __shared__ float sred[8];
    __shared__ float sbc[2];
    int b = blockIdx.x, tid = threadIdx.x;

    float val = -3.0e38f;
    if (tid <= NS) val = (tid == 0) ? 0.f : lg[(size_t)b * (NS + 1) + tid];

    float m = wred_max(val);
    if ((tid & 63) == 0) sred[tid >> 6] = m;
    __syncthreads();
    if (tid == 0) {
        float mm = sred[0];
        #pragma unroll
        for (int i = 1; i < 8; ++i) mm = fmaxf(mm, sred[i]);
        sbc[0] = mm;
    }
    __syncthreads();
    float mx = sbc[0];
    float e = (tid <= NS) ? expf(val - mx) : 0.f;
    float s = wred_sum(e);
    if ((tid & 63) == 0) sred[tid >> 6] = s;
    __syncthreads();
    if (tid == 0) {
        float t = 0.f;
        #pragma unroll
        for (int i = 0; i < 8; ++i) t += sred[i];
        sbc[1] = t;
    }
    __syncthreads();
    if (tid <= NS) out[(size_t)b * (NS + 1) + tid] = e / sbc[1];
}

extern "C" void kernel_launch(void* const* d_in, const int* in_sizes, int n_in,
                              void* d_out, int out_size, void* d_ws, size_t ws_size,
                              hipStream_t stream)
{
    const float* obs   = (const float*)d_in[0];
    const float* la    = (const float*)d_in[1];
    const int*   ei    = (const int*)d_in[2];
    const int*   et    = (const int*)d_in[3];
    const int*   nodes = (const int*)d_in[4];
    const float* ws1 = (const float*)d_in[5],  *bs1 = (const float*)d_in[6];
    const float* ws2 = (const float*)d_in[7],  *bs2 = (const float*)d_in[8];
    const float* wm1 = (const float*)d_in[9],  *bm1 = (const float*)d_in[10];
    const float* wm2 = (const float*)d_in[11], *bm2 = (const float*)d_in[12];
    const float* root1 = (const float*)d_in[13], *rel1 = (const float*)d_in[14], *bias1 = (const float*)d_in[15];
    const float* root2 = (const float*)d_in[16], *rel2 = (const float*)d_in[17], *bias2 = (const float*)d_in[18];
    const float* wf = (const float*)d_in[19], *bf = (const float*)d_in[20];

    float* wsp = (float*)d_ws;
    float* x   = wsp + XT_OFF;
    float* h1  = wsp + H1_OFF;
    float* lg  = wsp + LG_OFF;
    int*   ibase = (int*)(wsp + INT_BASE);
    int*   cnt   = ibase + CNT_OFF;
    int*   ebuf  = ibase + EBUF_OFF;

    hipMemsetAsync(cnt, 0, NBKT * sizeof(int), stream);

    // fused: phase A (0..749) + phase B (750..1499) + bucket fill (1500..1874)
    k_front<<<1875, 256, 0, stream>>>(
        obs, ws1, bs1, ws2, bs2, wm1, bm1, wm2, bm2, x, ei, et, cnt, ebuf);

    // RGCN layer 1: block per (node, batch-half), XCD-partitioned halves
    k_rgcn<false, false><<<NN * 2, 256, 0, stream>>>(
        x, nullptr, cnt, ebuf, nullptr, root1, rel1, bias1,
        nullptr, nullptr, nullptr, h1);

    // RGCN layer 2 (+ logits): block per (selected stock, batch-half)
    k_rgcn<true, true><<<NS * 2, 256, 0, stream>>>(
        h1, x, cnt, ebuf, nodes, root2, rel2, bias2,
        la, wf, bf, lg);

    k_softmax<<<NB, 512, 0, stream>>>(lg, (float*)d_out);
}